// Round 1
// baseline (2943.612 us; speedup 1.0000x reference)
//
#include <hip/hip_runtime.h>
#include <stdint.h>

#define BB 16
#define NN 2048
#define DD 128
#define CC 8

// ---------------------------------------------------------------------------
// K1: neighbors f32 [B,N,N] -> bitmask [B,N,N/32] u32. One wave per row.
// ---------------------------------------------------------------------------
__global__ __launch_bounds__(256) void k_buildbits(const float* __restrict__ nb,
                                                   uint32_t* __restrict__ rowbits) {
    int lane = threadIdx.x & 63;
    int wave = threadIdx.x >> 6;
    int row  = blockIdx.x * 4 + wave;                 // [0, BB*NN)
    const float* src = nb + (size_t)row * NN;
    uint64_t* dst = (uint64_t*)rowbits + (size_t)row * (NN / 64);
    for (int j = 0; j < NN / 64; j++) {
        float v = src[j * 64 + lane];                 // coalesced 256B
        uint64_t m = __ballot(v == 1.0f);             // bit l <-> element 64j+l
        if (lane == 0) dst[j] = m;
    }
}

// ---------------------------------------------------------------------------
// K2: serial greedy propagation. One wave (64 lanes) per batch.
// Lane l owns nodes [32l, 32l+32): conf in 32 registers, nbhd/unvis as u32.
// ---------------------------------------------------------------------------
template <bool USEBITS>
__global__ __launch_bounds__(64) void k_greedy(const float* __restrict__ confid,
                                               const uint32_t* __restrict__ rowbits,
                                               const float* __restrict__ nb,
                                               float* __restrict__ perm_out) {
    int b = blockIdx.x;
    int lane = threadIdx.x;

    // conf0 = max over 8 classes for each of my 32 nodes
    float conf[32];
    {
        const float* cb = confid + (size_t)b * NN * CC + (size_t)lane * 32 * CC;
        #pragma unroll
        for (int k = 0; k < 32; k++) {
            const float4* p = (const float4*)(cb + k * CC);
            float4 a = p[0], c = p[1];
            conf[k] = fmaxf(fmaxf(fmaxf(a.x, a.y), fmaxf(a.z, a.w)),
                            fmaxf(fmaxf(c.x, c.y), fmaxf(c.z, c.w)));
        }
    }

    uint32_t nbhd  = 0u;
    uint32_t unvis = 0xFFFFFFFFu;
    const uint32_t* rb  = rowbits + (size_t)b * NN * (NN / 32);
    const float*    nbb = nb      + (size_t)b * NN * NN;
    float*          po  = perm_out + (size_t)b * NN;

    for (int t = 0; t < NN; t++) {
        // ---- local masked argmax over my 32 nodes (ascending k + strict '>'
        //      keeps the smallest index on ties, matching JAX argmax) ----
        float bv = -1.0f; int bk = 0;
        #pragma unroll
        for (int k = 0; k < 32; k++) {
            float v = ((nbhd >> k) & 1u) ? conf[k] : -1.0f;
            bool g = v > bv;
            bv = g ? v : bv;
            bk = g ? k : bk;
        }
        // pack: (f32 bits << 32) | (NN - idx). conf >= 0 so bit-compare == value
        // compare; larger low-word == smaller index wins ties. 0 == "no member".
        unsigned long long pk = 0ULL;
        if (bv >= 0.0f)
            pk = ((unsigned long long)__float_as_uint(bv) << 32) |
                 (unsigned)(NN - (lane * 32 + bk));
        #pragma unroll
        for (int m = 32; m; m >>= 1) {
            unsigned long long o = __shfl_xor(pk, m, 64);
            pk = (o > pk) ? o : pk;
        }
        if (pk == 0ULL) {  // nbhd empty -> global argmax over all conf (wave-uniform branch)
            float av = conf[0]; int ak = 0;
            #pragma unroll
            for (int k = 1; k < 32; k++) {
                bool g = conf[k] > av;
                av = g ? conf[k] : av;
                ak = g ? k : ak;
            }
            unsigned long long pa =
                ((unsigned long long)__float_as_uint(av) << 32) |
                (unsigned)(NN - (lane * 32 + ak));
            #pragma unroll
            for (int m = 32; m; m >>= 1) {
                unsigned long long o = __shfl_xor(pa, m, 64);
                pa = (o > pa) ? o : pa;
            }
            pk = pa;
        }
        int fc = NN - (int)(unsigned)(pk & 0xFFFFFFFFull);

        // ---- issue row fetch ASAP (critical path) ----
        uint32_t row;
        if (USEBITS) {
            row = rb[(size_t)fc * (NN / 32) + lane];      // one coalesced 256B load
        } else {
            const float4* rp = (const float4*)(nbb + (size_t)fc * NN + lane * 32);
            row = 0u;
            #pragma unroll
            for (int j = 0; j < 8; j++) {
                float4 f = rp[j];
                row |= (f.x == 1.0f ? 1u : 0u) << (4 * j);
                row |= (f.y == 1.0f ? 1u : 0u) << (4 * j + 1);
                row |= (f.z == 1.0f ? 1u : 0u) << (4 * j + 2);
                row |= (f.w == 1.0f ? 1u : 0u) << (4 * j + 3);
            }
        }

        // ---- broadcast conf[fc] (unrolled select avoids scratch; hidden under load) ----
        int kf = fc & 31, owner = fc >> 5;
        float sel = conf[0];
        #pragma unroll
        for (int k = 1; k < 32; k++) sel = (kf == k) ? conf[k] : sel;
        float cfc = __shfl(sel, owner, 64);

        if (lane == 0) po[t] = (float)fc;

        // ---- state update, reference order ----
        if (lane == owner) nbhd &= ~(1u << kf);           // nbhd.remove(fc)
        // tie-zeroing: conf *= (conf != conf[fc]); cfc==0 => no change (0 stays 0)
        #pragma unroll
        for (int k = 0; k < 32; k++) conf[k] = (conf[k] == cfc) ? 0.0f : conf[k];
        nbhd |= (row & unvis);                            // add unvisited neighbors of fc
        if (lane == owner) unvis &= ~(1u << kf);          // unvis.remove(fc)
    }
}

// ---------------------------------------------------------------------------
// K3: out0[b,t,:] = vertices[b, perm[t], :]
// ---------------------------------------------------------------------------
__global__ __launch_bounds__(256) void k_gather(const float* __restrict__ vtx,
                                                const float* __restrict__ perm_f,
                                                float* __restrict__ out0) {
    int tid = blockIdx.x * 256 + threadIdx.x;             // [0, BB*NN*DD)
    int d = tid & (DD - 1);
    int t = (tid >> 7) & (NN - 1);
    int b = tid >> 18;
    int p = (int)perm_f[b * NN + t];
    out0[tid] = vtx[(((size_t)b * NN + p) << 7) + d];
}

// ---------------------------------------------------------------------------
extern "C" void kernel_launch(void* const* d_in, const int* in_sizes, int n_in,
                              void* d_out, int out_size, void* d_ws, size_t ws_size,
                              hipStream_t stream) {
    const float* vertices   = (const float*)d_in[0];   // [B,N,D]
    const float* confidence = (const float*)d_in[1];   // [B,N,C]
    const float* neighbors  = (const float*)d_in[2];   // [B,N,N]

    float* out0     = (float*)d_out;                   // [B,N,D] f32
    float* perm_out = out0 + (size_t)BB * NN * DD;     // [B,N] written as f32 values

    const size_t bits_bytes = (size_t)BB * NN * (NN / 8);   // 8 MB
    uint32_t* rowbits = (uint32_t*)d_ws;
    bool use_bits = (ws_size >= bits_bytes);

    if (use_bits) {
        k_buildbits<<<BB * NN / 4, 256, 0, stream>>>(neighbors, rowbits);
        k_greedy<true><<<BB, 64, 0, stream>>>(confidence, rowbits, neighbors, perm_out);
    } else {
        k_greedy<false><<<BB, 64, 0, stream>>>(confidence, rowbits, neighbors, perm_out);
    }
    k_gather<<<(BB * NN * DD) / 256, 256, 0, stream>>>(vertices, perm_out, out0);
}

// Round 2
// 2356.924 us; speedup vs baseline: 1.2489x; 1.2489x over previous
//
#include <hip/hip_runtime.h>
#include <stdint.h>

#define BB 16
#define NN 2048
#define DD 128
#define CC 8

typedef unsigned long long u64;

// ---------------------------------------------------------------------------
// K1: neighbors f32 [B,N,N] -> bitmask [B,N,N/32] u32. One wave per row.
// ---------------------------------------------------------------------------
__global__ __launch_bounds__(256) void k_buildbits(const float* __restrict__ nb,
                                                   uint32_t* __restrict__ rowbits) {
    int lane = threadIdx.x & 63;
    int wave = threadIdx.x >> 6;
    int row  = blockIdx.x * 4 + wave;                 // [0, BB*NN)
    const float* src = nb + (size_t)row * NN;
    uint64_t* dst = (uint64_t*)rowbits + (size_t)row * (NN / 64);
    for (int j = 0; j < NN / 64; j++) {
        float v = src[j * 64 + lane];                 // coalesced 256B
        uint64_t m = __ballot(v == 1.0f);             // bit l <-> element 64j+l
        if (lane == 0) dst[j] = m;
    }
}

// ---------------------------------------------------------------------------
// Cross-lane helpers: DPP butterfly (VALU latency) + readlane finish.
// ---------------------------------------------------------------------------
template <int CTRL>
__device__ __forceinline__ u64 dppmax64(u64 v) {
    int lo = (int)(unsigned)(v & 0xFFFFFFFFu);
    int hi = (int)(unsigned)(v >> 32);
    int plo = __builtin_amdgcn_update_dpp(lo, lo, CTRL, 0xF, 0xF, false);
    int phi = __builtin_amdgcn_update_dpp(hi, hi, CTRL, 0xF, 0xF, false);
    u64 o = ((u64)(unsigned)phi << 32) | (unsigned)plo;
    return o > v ? o : v;
}

__device__ __forceinline__ u64 rdlane64(u64 v, int l) {
    unsigned lo = (unsigned)__builtin_amdgcn_readlane((int)(unsigned)(v & 0xFFFFFFFFu), l);
    unsigned hi = (unsigned)__builtin_amdgcn_readlane((int)(unsigned)(v >> 32), l);
    return ((u64)hi << 32) | lo;
}

// Full-wave max of packed u64; result is wave-uniform (lives in SGPRs).
__device__ __forceinline__ u64 wavemax64(u64 pk) {
    pk = dppmax64<0xB1>(pk);    // quad_perm [1,0,3,2]  = xor 1
    pk = dppmax64<0x4E>(pk);    // quad_perm [2,3,0,1]  = xor 2
    pk = dppmax64<0x141>(pk);   // row_half_mirror      = xor 7
    pk = dppmax64<0x140>(pk);   // row_mirror           = xor 15  -> row-16 max
    u64 a = rdlane64(pk, 0);
    u64 b = rdlane64(pk, 16);
    u64 c = rdlane64(pk, 32);
    u64 d = rdlane64(pk, 48);
    u64 ab = a > b ? a : b;
    u64 cd = c > d ? c : d;
    return ab > cd ? ab : cd;
}

// Per-lane argmax over 32 owned nodes via pair-tree (short dep chain).
// Returns packed (f32 bits << 32) | (NN - global_idx); 0 == "no member".
// Ascending-index winner on exact ties (matches JAX argmax).
template <bool MASKED>
__device__ __forceinline__ u64 lane_argmax(const float (&conf)[32], uint32_t nbhd,
                                           int laneKey) {
    float tv[32];
    int   ti[32];
#pragma unroll
    for (int k = 0; k < 32; k++) {
        tv[k] = (!MASKED || ((int)(nbhd << (31 - k)) < 0)) ? conf[k] : -1.0f;
        ti[k] = k;
    }
#pragma unroll
    for (int s = 16; s; s >>= 1) {
#pragma unroll
        for (int j = 0; j < s; j++) {
            bool g = tv[j + s] > tv[j];   // strict: lower index wins ties
            tv[j] = g ? tv[j + s] : tv[j];
            ti[j] = g ? ti[j + s] : ti[j];
        }
    }
    u64 pk = ((u64)__float_as_uint(tv[0]) << 32) | (unsigned)(laneKey - ti[0]);
    if (MASKED && tv[0] < 0.0f) pk = 0ULL;
    return pk;
}

// ---------------------------------------------------------------------------
// K2: serial greedy propagation. One wave per batch; lane l owns nodes
// [32l, 32l+32): conf in 32 registers, nbhd/unvis as u32 bitmasks.
// ---------------------------------------------------------------------------
template <bool USEBITS>
__global__ __launch_bounds__(64, 1) void k_greedy(const float* __restrict__ confid,
                                                  const uint32_t* __restrict__ rowbits,
                                                  const float* __restrict__ nb,
                                                  float* __restrict__ perm_out) {
    int b = blockIdx.x;
    int lane = threadIdx.x;

    // conf0 = max over 8 classes for each of my 32 nodes
    float conf[32];
    {
        const float* cb = confid + (size_t)b * NN * CC + (size_t)lane * 32 * CC;
#pragma unroll
        for (int k = 0; k < 32; k++) {
            const float4* p = (const float4*)(cb + k * CC);
            float4 a = p[0], c = p[1];
            conf[k] = fmaxf(fmaxf(fmaxf(a.x, a.y), fmaxf(a.z, a.w)),
                            fmaxf(fmaxf(c.x, c.y), fmaxf(c.z, c.w)));
        }
    }

    uint32_t nbhd  = 0u;
    uint32_t unvis = 0xFFFFFFFFu;
    const uint32_t* rb  = rowbits + (size_t)b * NN * (NN / 32);
    const float*    nbb = nb      + (size_t)b * NN * NN;
    float*          po  = perm_out + (size_t)b * NN;
    const int laneKey = NN - lane * 32;

    for (int t = 0; t < NN; t++) {
        // ---- masked argmax (tree + DPP reduce); fc, cfc end up uniform ----
        u64 best = wavemax64(lane_argmax<true>(conf, nbhd, laneKey));
        if (best == 0ULL) {   // nbhd empty -> global argmax (wave-uniform, rare)
            best = wavemax64(lane_argmax<false>(conf, nbhd, laneKey));
        }
        int   fc  = NN - (int)(unsigned)(best & 0xFFFFFFFFu);
        float cfc = __uint_as_float((unsigned)(best >> 32));   // == conf[fc], free

        // ---- issue row fetch ASAP (SGPR base + lane offset) ----
        uint32_t row;
        if (USEBITS) {
            row = rb[(unsigned)fc * (NN / 32) + (unsigned)lane];  // 256B coalesced
        } else {
            const float4* rp = (const float4*)(nbb + (size_t)fc * NN + lane * 32);
            row = 0u;
#pragma unroll
            for (int j = 0; j < 8; j++) {
                float4 f = rp[j];
                row |= (f.x == 1.0f ? 1u : 0u) << (4 * j);
                row |= (f.y == 1.0f ? 1u : 0u) << (4 * j + 1);
                row |= (f.z == 1.0f ? 1u : 0u) << (4 * j + 2);
                row |= (f.w == 1.0f ? 1u : 0u) << (4 * j + 3);
            }
        }

        if (lane == 0) po[t] = (float)fc;

        // ---- state update (overlaps with row load latency) ----
        uint32_t mybit = (lane == (fc >> 5)) ? (1u << (fc & 31)) : 0u;
        // tie-zeroing: conf *= (conf != conf[fc])
#pragma unroll
        for (int k = 0; k < 32; k++) conf[k] = (conf[k] == cfc) ? 0.0f : conf[k];
        nbhd  = (nbhd & ~mybit) | (row & unvis);  // remove fc, add unvisited nbrs
        unvis &= ~mybit;                          // visit fc
    }
}

// ---------------------------------------------------------------------------
// K3: out0[b,t,:] = vertices[b, perm[t], :]
// ---------------------------------------------------------------------------
__global__ __launch_bounds__(256) void k_gather(const float* __restrict__ vtx,
                                                const float* __restrict__ perm_f,
                                                float* __restrict__ out0) {
    int tid = blockIdx.x * 256 + threadIdx.x;             // [0, BB*NN*DD)
    int d = tid & (DD - 1);
    int t = (tid >> 7) & (NN - 1);
    int b = tid >> 18;
    int p = (int)perm_f[b * NN + t];
    out0[tid] = vtx[(((size_t)b * NN + p) << 7) + d];
}

// ---------------------------------------------------------------------------
extern "C" void kernel_launch(void* const* d_in, const int* in_sizes, int n_in,
                              void* d_out, int out_size, void* d_ws, size_t ws_size,
                              hipStream_t stream) {
    const float* vertices   = (const float*)d_in[0];   // [B,N,D]
    const float* confidence = (const float*)d_in[1];   // [B,N,C]
    const float* neighbors  = (const float*)d_in[2];   // [B,N,N]

    float* out0     = (float*)d_out;                   // [B,N,D] f32
    float* perm_out = out0 + (size_t)BB * NN * DD;     // [B,N] written as f32 values

    const size_t bits_bytes = (size_t)BB * NN * (NN / 8);   // 8 MB
    uint32_t* rowbits = (uint32_t*)d_ws;
    bool use_bits = (ws_size >= bits_bytes);

    if (use_bits) {
        k_buildbits<<<BB * NN / 4, 256, 0, stream>>>(neighbors, rowbits);
        k_greedy<true><<<BB, 64, 0, stream>>>(confidence, rowbits, neighbors, perm_out);
    } else {
        k_greedy<false><<<BB, 64, 0, stream>>>(confidence, rowbits, neighbors, perm_out);
    }
    k_gather<<<(BB * NN * DD) / 256, 256, 0, stream>>>(vertices, perm_out, out0);
}

// Round 3
// 1237.087 us; speedup vs baseline: 2.3795x; 1.9052x over previous
//
#include <hip/hip_runtime.h>
#include <stdint.h>

#define BB 16
#define NN 2048
#define DD 128
#define CC 8

typedef unsigned long long u64;

// ===========================================================================
// P2: per-batch sort by (conf desc, idx asc) + run extents for tie-zeroing.
// One block of 256 threads per batch; bitonic sort of 2048 u64 keys in LDS.
// Outputs (per batch): orig[p] (sorted pos -> orig idx), inv[i] (orig -> pos),
// runExt[p] = (runEnd<<16)|runStart of the equal-conf run containing p.
// ===========================================================================
__global__ __launch_bounds__(256) void k_sort(const float* __restrict__ confid,
                                              uint32_t* __restrict__ orig,
                                              uint32_t* __restrict__ inv,
                                              uint32_t* __restrict__ runExt) {
    __shared__ u64 keys[NN];          // 16 KB
    __shared__ uint32_t scan[NN];     // 8 KB
    __shared__ uint32_t rstart[NN];   // 8 KB
    int b = blockIdx.x, tid = threadIdx.x;
    const float* cb = confid + (size_t)b * NN * CC;

    for (int i = tid; i < NN; i += 256) {
        const float4* p4 = (const float4*)(cb + (size_t)i * CC);
        float4 a = p4[0], c = p4[1];
        float cf = fmaxf(fmaxf(fmaxf(a.x, a.y), fmaxf(a.z, a.w)),
                         fmaxf(fmaxf(c.x, c.y), fmaxf(c.z, c.w)));
        // descending by conf bits (conf>=0), ties -> smaller idx first
        keys[i] = ((u64)__float_as_uint(cf) << 32) | (uint32_t)(NN - 1 - i);
    }
    __syncthreads();

    for (int k = 2; k <= NN; k <<= 1) {
        for (int j = k >> 1; j > 0; j >>= 1) {
            for (int i = tid; i < NN; i += 256) {
                int ixj = i ^ j;
                if (ixj > i) {
                    bool up = ((i & k) == 0);
                    u64 a = keys[i], c = keys[ixj];
                    if ((a < c) == up) { keys[i] = c; keys[ixj] = a; }  // descending
                }
            }
            __syncthreads();
        }
    }

    for (int p = tid; p < NN; p += 256) {
        uint32_t og = (uint32_t)(NN - 1) - (uint32_t)(keys[p] & 0xFFFFFFFFu);
        orig[b * NN + p] = og;
        inv[b * NN + og] = (uint32_t)p;
    }

    // runStart: prefix-max of (tie ? 0 : p)
    __syncthreads();
    for (int p = tid; p < NN; p += 256) {
        bool tie = (p > 0) && ((uint32_t)(keys[p] >> 32) == (uint32_t)(keys[p - 1] >> 32));
        scan[p] = tie ? 0u : (uint32_t)p;
    }
    __syncthreads();
    for (int s = 1; s < NN; s <<= 1) {
        uint32_t v[8];
        for (int p = tid, q = 0; p < NN; p += 256, q++)
            v[q] = (p >= s) ? max(scan[p], scan[p - s]) : scan[p];
        __syncthreads();
        for (int p = tid, q = 0; p < NN; p += 256, q++) scan[p] = v[q];
        __syncthreads();
    }
    for (int p = tid; p < NN; p += 256) rstart[p] = scan[p];

    // runEnd: suffix-min of (tieNext ? BIG : p)
    __syncthreads();
    for (int p = tid; p < NN; p += 256) {
        bool tieN = (p < NN - 1) &&
                    ((uint32_t)(keys[p + 1] >> 32) == (uint32_t)(keys[p] >> 32));
        scan[p] = tieN ? 0x7FFFFFFFu : (uint32_t)p;
    }
    __syncthreads();
    for (int s = 1; s < NN; s <<= 1) {
        uint32_t v[8];
        for (int p = tid, q = 0; p < NN; p += 256, q++)
            v[q] = (p + s < NN) ? min(scan[p], scan[p + s]) : scan[p];
        __syncthreads();
        for (int p = tid, q = 0; p < NN; p += 256, q++) scan[p] = v[q];
        __syncthreads();
    }
    for (int p = tid; p < NN; p += 256)
        runExt[b * NN + p] = (scan[p] << 16) | rstart[p];
}

// ===========================================================================
// P3: permuted adjacency bit-matrix. rowS[b][p][l] bit k =
//     (neighbors[b][orig[p]][orig[32l+k]] == 1.0). One wave per 8 rows.
// ===========================================================================
__global__ __launch_bounds__(256, 1) void k_permmat(const float* __restrict__ nb,
                                                    const uint32_t* __restrict__ orig,
                                                    uint32_t* __restrict__ rowS) {
    int lane = threadIdx.x & 63, wave = threadIdx.x >> 6;
    int rowsBase = blockIdx.x * 32 + wave * 8;   // [0, BB*NN)
    int b = rowsBase >> 11;
    int pBase = rowsBase & (NN - 1);
    const uint32_t* ob = orig + b * NN;

    uint32_t cols[32];
#pragma unroll
    for (int k = 0; k < 32; k++) cols[k] = ob[lane * 32 + k];

    const float* nbB = nb + (size_t)b * NN * NN;
    for (int r = 0; r < 8; r++) {
        int p = pBase + r;
        const float* rowp = nbB + (size_t)ob[p] * NN;
        uint32_t wbits = 0;
#pragma unroll
        for (int k = 0; k < 32; k++)
            wbits |= (rowp[cols[k]] == 1.0f ? 1u : 0u) << k;
        rowS[((size_t)b * NN + p) * 64 + lane] = wbits;
    }
}

// ===========================================================================
// K2: serial greedy in sorted domain. One wave per batch.
// Lane l holds bits [32l,32l+32) of: avail (conf>0), nbhd, unvis.
// Selection = first set bit (ballot + ff1); tie-zero = clear run [rs,re].
// ===========================================================================
__global__ __launch_bounds__(64, 1) void k_greedy2(const uint32_t* __restrict__ rowS,
                                                   const uint32_t* __restrict__ orig,
                                                   const uint32_t* __restrict__ inv,
                                                   const uint32_t* __restrict__ runExt,
                                                   float* __restrict__ perm_out) {
    int b = blockIdx.x, lane = threadIdx.x;
    const uint32_t* rS = rowS + (size_t)b * NN * 64;
    const uint32_t* ob = orig + b * NN;
    const uint32_t* ib = inv + b * NN;
    const uint32_t* rE = runExt + b * NN;
    float* po = perm_out + b * NN;

    uint32_t availW = 0xFFFFFFFFu, nbhdW = 0u, unvisW = 0xFFFFFFFFu;

    for (int t = 0; t < NN; t++) {
        uint32_t w = nbhdW & availW;
        u64 m = __ballot(w != 0u);
        int p;
        bool positive;
        if (m) {                                   // fast path: best positive in nbhd
            int L = __ffsll(m) - 1;
            uint32_t wl = (uint32_t)__builtin_amdgcn_readlane((int)w, L);
            p = L * 32 + (__ffs(wl) - 1);
            positive = true;
        } else if (__ballot(nbhdW != 0u)) {        // rare: nbhd nonempty, all zeroed
            uint32_t nw = nbhdW, mo = 0xFFFFFFFFu; // -> min orig index among nbhd
            while (nw) {
                int k = __ffs(nw) - 1; nw &= nw - 1;
                mo = min(mo, ob[lane * 32 + k]);
            }
#pragma unroll
            for (int s = 32; s; s >>= 1)
                mo = min(mo, (uint32_t)__shfl_xor((int)mo, s, 64));
            p = (int)ib[mo];
            positive = false;
        } else {                                   // nbhd empty: global argmax
            u64 ma = __ballot(availW != 0u);
            if (ma) {
                int L = __ffsll(ma) - 1;
                uint32_t wl = (uint32_t)__builtin_amdgcn_readlane((int)availW, L);
                p = L * 32 + (__ffs(wl) - 1);
                positive = true;
            } else {                               // all conf zero -> argmax = idx 0
                p = (int)ib[0];
                positive = false;
            }
        }
        p = __builtin_amdgcn_readfirstlane(p);

        uint32_t rowW = rS[(size_t)p * 64 + lane];   // 256B coalesced, read-once
        uint32_t ext  = rE[p];                        // uniform -> scalar load
        uint32_t ogv  = ob[p];                        // uniform -> scalar load

        if (lane == 0) po[t] = (float)ogv;

        if (positive) {                               // clear equal-conf run in avail
            int rs  = (int)(ext & 0xFFFFu);
            int ren = (int)(ext >> 16);
            int lo = rs - lane * 32;      lo = lo < 0 ? 0 : (lo > 32 ? 32 : lo);
            int hi = ren + 1 - lane * 32; hi = hi < 0 ? 0 : (hi > 32 ? 32 : hi);
            if (hi > lo) {
                uint32_t mh = (hi >= 32) ? 0xFFFFFFFFu : ((1u << hi) - 1u);
                uint32_t ml = (1u << lo) - 1u;
                availW &= ~(mh & ~ml);
            }
        }
        uint32_t pbit = (lane == (p >> 5)) ? (1u << (p & 31)) : 0u;
        nbhdW = (nbhdW & ~pbit) | (rowW & unvisW);    // remove fc, add unvisited nbrs
        unvisW &= ~pbit;                              // visit fc
    }
}

// ===========================================================================
// Fallback (ws too small): direct-f32 greedy, contiguous-lane ownership.
// ===========================================================================
__global__ __launch_bounds__(64, 1) void k_greedy_fb(const float* __restrict__ confid,
                                                     const float* __restrict__ nb,
                                                     float* __restrict__ perm_out) {
    int b = blockIdx.x, lane = threadIdx.x;
    float conf[32];
    {
        const float* cb = confid + (size_t)b * NN * CC + (size_t)lane * 32 * CC;
#pragma unroll
        for (int k = 0; k < 32; k++) {
            const float4* p = (const float4*)(cb + k * CC);
            float4 a = p[0], c = p[1];
            conf[k] = fmaxf(fmaxf(fmaxf(a.x, a.y), fmaxf(a.z, a.w)),
                            fmaxf(fmaxf(c.x, c.y), fmaxf(c.z, c.w)));
        }
    }
    uint32_t nbhd = 0u, unvis = 0xFFFFFFFFu;
    const float* nbb = nb + (size_t)b * NN * NN;
    float* po = perm_out + (size_t)b * NN;
    for (int t = 0; t < NN; t++) {
        float bv = -1.0f; int bk = 0;
#pragma unroll
        for (int k = 0; k < 32; k++) {
            float v = ((nbhd >> k) & 1u) ? conf[k] : -1.0f;
            bool g = v > bv; bv = g ? v : bv; bk = g ? k : bk;
        }
        u64 pk = 0ULL;
        if (bv >= 0.0f)
            pk = ((u64)__float_as_uint(bv) << 32) | (unsigned)(NN - (lane * 32 + bk));
#pragma unroll
        for (int mm = 32; mm; mm >>= 1) {
            u64 o = __shfl_xor(pk, mm, 64);
            pk = (o > pk) ? o : pk;
        }
        if (pk == 0ULL) {
            float av = conf[0]; int ak = 0;
#pragma unroll
            for (int k = 1; k < 32; k++) {
                bool g = conf[k] > av; av = g ? conf[k] : av; ak = g ? k : ak;
            }
            u64 pa = ((u64)__float_as_uint(av) << 32) | (unsigned)(NN - (lane * 32 + ak));
#pragma unroll
            for (int mm = 32; mm; mm >>= 1) {
                u64 o = __shfl_xor(pa, mm, 64);
                pa = (o > pa) ? o : pa;
            }
            pk = pa;
        }
        int fc = NN - (int)(unsigned)(pk & 0xFFFFFFFFull);
        float cfc = __uint_as_float((unsigned)(pk >> 32));
        const float4* rp = (const float4*)(nbb + (size_t)fc * NN + lane * 32);
        uint32_t row = 0u;
#pragma unroll
        for (int j = 0; j < 8; j++) {
            float4 f = rp[j];
            row |= (f.x == 1.0f ? 1u : 0u) << (4 * j);
            row |= (f.y == 1.0f ? 1u : 0u) << (4 * j + 1);
            row |= (f.z == 1.0f ? 1u : 0u) << (4 * j + 2);
            row |= (f.w == 1.0f ? 1u : 0u) << (4 * j + 3);
        }
        if (lane == 0) po[t] = (float)fc;
        uint32_t mybit = (lane == (fc >> 5)) ? (1u << (fc & 31)) : 0u;
#pragma unroll
        for (int k = 0; k < 32; k++) conf[k] = (conf[k] == cfc) ? 0.0f : conf[k];
        nbhd = (nbhd & ~mybit) | (row & unvis);
        unvis &= ~mybit;
    }
}

// ===========================================================================
// K3: out0[b,t,:] = vertices[b, perm[t], :]
// ===========================================================================
__global__ __launch_bounds__(256) void k_gather(const float* __restrict__ vtx,
                                                const float* __restrict__ perm_f,
                                                float* __restrict__ out0) {
    int tid = blockIdx.x * 256 + threadIdx.x;
    int d = tid & (DD - 1);
    int t = (tid >> 7) & (NN - 1);
    int b = tid >> 18;
    int p = (int)perm_f[b * NN + t];
    out0[tid] = vtx[(((size_t)b * NN + p) << 7) + d];
}

// ===========================================================================
extern "C" void kernel_launch(void* const* d_in, const int* in_sizes, int n_in,
                              void* d_out, int out_size, void* d_ws, size_t ws_size,
                              hipStream_t stream) {
    const float* vertices   = (const float*)d_in[0];
    const float* confidence = (const float*)d_in[1];
    const float* neighbors  = (const float*)d_in[2];

    float* out0     = (float*)d_out;                   // [B,N,D]
    float* perm_out = out0 + (size_t)BB * NN * DD;     // [B,N] as f32 values

    const size_t rowS_bytes = (size_t)BB * NN * (NN / 8);   // 8 MB exactly
    if (ws_size >= rowS_bytes) {
        uint32_t* rowS = (uint32_t*)d_ws;
        // small tables live in the out0 region (fully overwritten by k_gather)
        uint32_t* orig   = (uint32_t*)out0;            // BB*NN u32 = 128 KB
        uint32_t* inv    = orig + BB * NN;             // 128 KB
        uint32_t* runExt = inv + BB * NN;              // 128 KB  (total 384 KB << 16 MB)

        k_sort<<<BB, 256, 0, stream>>>(confidence, orig, inv, runExt);
        k_permmat<<<BB * NN / 32, 256, 0, stream>>>(neighbors, orig, rowS);
        k_greedy2<<<BB, 64, 0, stream>>>(rowS, orig, inv, runExt, perm_out);
    } else {
        k_greedy_fb<<<BB, 64, 0, stream>>>(confidence, neighbors, perm_out);
    }
    k_gather<<<(BB * NN * DD) / 256, 256, 0, stream>>>(vertices, perm_out, out0);
}

// Round 4
// 682.327 us; speedup vs baseline: 4.3141x; 1.8130x over previous
//
#include <hip/hip_runtime.h>
#include <stdint.h>

#define BB 16
#define NN 2048
#define DD 128
#define CC 8

typedef unsigned long long u64;

// ===========================================================================
// K1: neighbors f32 [B,N,N] -> unpermuted bitmask bits[b][r][w] (w: 64 u32,
// bit c&31 of word c>>5 = (neighbors[b][r][c]==1)). One wave per row,
// fully coalesced 256B reads + ballot.
// ===========================================================================
__global__ __launch_bounds__(256) void k_buildbits(const float* __restrict__ nb,
                                                   uint32_t* __restrict__ bits) {
    int lane = threadIdx.x & 63;
    int wave = threadIdx.x >> 6;
    int row  = blockIdx.x * 4 + wave;                 // [0, BB*NN)
    const float* src = nb + (size_t)row * NN;
    uint64_t* dst = (uint64_t*)bits + (size_t)row * (NN / 64);
    for (int j = 0; j < NN / 64; j++) {
        float v = src[j * 64 + lane];                 // coalesced 256B
        uint64_t m = __ballot(v == 1.0f);             // bit l <-> col 64j+l
        if (lane == 0) dst[j] = m;
    }
}

// ===========================================================================
// P2: per-batch sort by (conf desc, idx asc); outputs orig/inv/runExt and
// packed singleton-run flags (bit k of word l = run at pos 32l+k has len 1).
// ===========================================================================
__global__ __launch_bounds__(256) void k_sort(const float* __restrict__ confid,
                                              uint32_t* __restrict__ orig,
                                              uint32_t* __restrict__ inv,
                                              uint32_t* __restrict__ runExt,
                                              uint32_t* __restrict__ singBits) {
    __shared__ u64 keys[NN];          // 16 KB
    __shared__ uint32_t scan[NN];     // 8 KB
    __shared__ uint32_t rstart[NN];   // 8 KB
    int b = blockIdx.x, tid = threadIdx.x;
    const float* cb = confid + (size_t)b * NN * CC;

    for (int i = tid; i < NN; i += 256) {
        const float4* p4 = (const float4*)(cb + (size_t)i * CC);
        float4 a = p4[0], c = p4[1];
        float cf = fmaxf(fmaxf(fmaxf(a.x, a.y), fmaxf(a.z, a.w)),
                         fmaxf(fmaxf(c.x, c.y), fmaxf(c.z, c.w)));
        keys[i] = ((u64)__float_as_uint(cf) << 32) | (uint32_t)(NN - 1 - i);
    }
    __syncthreads();

    for (int k = 2; k <= NN; k <<= 1) {
        for (int j = k >> 1; j > 0; j >>= 1) {
            for (int i = tid; i < NN; i += 256) {
                int ixj = i ^ j;
                if (ixj > i) {
                    bool up = ((i & k) == 0);
                    u64 a = keys[i], c = keys[ixj];
                    if ((a < c) == up) { keys[i] = c; keys[ixj] = a; }  // descending
                }
            }
            __syncthreads();
        }
    }

    for (int p = tid; p < NN; p += 256) {
        uint32_t og = (uint32_t)(NN - 1) - (uint32_t)(keys[p] & 0xFFFFFFFFu);
        orig[b * NN + p] = og;
        inv[b * NN + og] = (uint32_t)p;
    }

    // runStart: prefix-max of (tie ? 0 : p)
    __syncthreads();
    for (int p = tid; p < NN; p += 256) {
        bool tie = (p > 0) && ((uint32_t)(keys[p] >> 32) == (uint32_t)(keys[p - 1] >> 32));
        scan[p] = tie ? 0u : (uint32_t)p;
    }
    __syncthreads();
    for (int s = 1; s < NN; s <<= 1) {
        uint32_t v[8];
        for (int p = tid, q = 0; p < NN; p += 256, q++)
            v[q] = (p >= s) ? max(scan[p], scan[p - s]) : scan[p];
        __syncthreads();
        for (int p = tid, q = 0; p < NN; p += 256, q++) scan[p] = v[q];
        __syncthreads();
    }
    for (int p = tid; p < NN; p += 256) rstart[p] = scan[p];

    // runEnd: suffix-min of (tieNext ? BIG : p)
    __syncthreads();
    for (int p = tid; p < NN; p += 256) {
        bool tieN = (p < NN - 1) &&
                    ((uint32_t)(keys[p + 1] >> 32) == (uint32_t)(keys[p] >> 32));
        scan[p] = tieN ? 0x7FFFFFFFu : (uint32_t)p;
    }
    __syncthreads();
    for (int s = 1; s < NN; s <<= 1) {
        uint32_t v[8];
        for (int p = tid, q = 0; p < NN; p += 256, q++)
            v[q] = (p + s < NN) ? min(scan[p], scan[p + s]) : scan[p];
        __syncthreads();
        for (int p = tid, q = 0; p < NN; p += 256, q++) scan[p] = v[q];
        __syncthreads();
    }
    for (int p = tid; p < NN; p += 256)
        runExt[b * NN + p] = (scan[p] << 16) | rstart[p];

    __syncthreads();
    if (tid < 64) {   // pack singleton flags: pos 32*tid+k
        uint32_t sw = 0;
        for (int k = 0; k < 32; k++) {
            int p = tid * 32 + k;
            sw |= (rstart[p] == scan[p]) ? (1u << k) : 0u;
        }
        singBits[b * 64 + tid] = sw;
    }
}

// ===========================================================================
// P3: permute adjacency in BIT domain: rowS[b][p][l] bit k =
//     bits[b][orig[p]] bit orig[32l+k]. One wave per 32 rows, row via LDS.
// ===========================================================================
__global__ __launch_bounds__(256) void k_permbits(const uint32_t* __restrict__ bits,
                                                  const uint32_t* __restrict__ orig,
                                                  uint32_t* __restrict__ rowS) {
    __shared__ uint32_t rowLds[4][64];
    int lane = threadIdx.x & 63, wid = threadIdx.x >> 6;
    int waveG = blockIdx.x * 4 + wid;      // [0, 1024): 64 waves per batch
    int b = waveG >> 6;
    int wInB = waveG & 63;
    const uint32_t* ob = orig + b * NN;

    uint32_t ocol[32];                      // my 32 columns' orig indices
    const uint4* obv = (const uint4*)(ob + lane * 32);
#pragma unroll
    for (int q = 0; q < 8; q++) {
        uint4 v = obv[q];
        ocol[q * 4 + 0] = v.x; ocol[q * 4 + 1] = v.y;
        ocol[q * 4 + 2] = v.z; ocol[q * 4 + 3] = v.w;
    }

    const uint32_t* bitsB = bits + (size_t)b * NN * 64;
    uint32_t* rsB = rowS + (size_t)b * NN * 64;
    for (int r = 0; r < 32; r++) {
        int p = wInB * 32 + r;
        const uint32_t* src = bitsB + (size_t)ob[p] * 64;
        rowLds[wid][lane] = src[lane];      // in-wave DS ordering guarantees RAW
        uint32_t wb = 0;
#pragma unroll
        for (int k = 0; k < 32; k++) {
            uint32_t c = ocol[k];
            wb |= ((rowLds[wid][c >> 5] >> (c & 31)) & 1u) << k;
        }
        rsB[(size_t)p * 64 + lane] = wb;
    }
}

// ===========================================================================
// K2: serial greedy in sorted domain. Wave 0 = serial loop; waves 1-3 warm
// this batch's 512KB rowS slice into the local XCD L2.
// ===========================================================================
__global__ __launch_bounds__(256, 1) void k_greedy2(const uint32_t* __restrict__ rowS,
                                                    const uint32_t* __restrict__ orig,
                                                    const uint32_t* __restrict__ inv,
                                                    const uint32_t* __restrict__ runExt,
                                                    const uint32_t* __restrict__ singBits,
                                                    float* __restrict__ perm_out) {
    int b = blockIdx.x;
    int lane = threadIdx.x & 63;
    int wid  = threadIdx.x >> 6;
    const uint32_t* rS = rowS + (size_t)b * NN * 64;

    if (wid > 0) {
        // ---- L2 warmers: stream 512KB slice, 8 loads in flight, 2 passes ----
        const uint4* src = (const uint4*)rS;           // NN*16 uint4
        uint32_t acc = 0;
        for (int pass = 0; pass < 2; pass++) {
            for (int i = (wid - 1) * 64 + lane; i < NN * 16; i += 192 * 8) {
                uint32_t a0 = 0;
#pragma unroll
                for (int u = 0; u < 8; u++) {
                    int j = i + u * 192;
                    if (j < NN * 16) {
                        uint4 v = src[j];
                        a0 ^= v.x ^ v.y ^ v.z ^ v.w;
                    }
                }
                acc ^= a0;
            }
        }
        asm volatile("" :: "v"(acc));                  // keep loads live
        return;
    }

    __builtin_amdgcn_s_setprio(1);
    const uint32_t* ob = orig + b * NN;
    const uint32_t* ib = inv + b * NN;
    const uint32_t* rE = runExt + b * NN;
    float* po = perm_out + b * NN;

    uint32_t availW = 0xFFFFFFFFu, nbhdW = 0u, unvisW = 0xFFFFFFFFu;
    uint32_t nonSingW = ~singBits[b * 64 + lane];      // bit k: pos 32*lane+k in a tie-run

    for (int t = 0; t < NN; t++) {
        uint32_t w = nbhdW & availW;
        u64 m = __ballot(w != 0u);
        int p;
        bool positive;
        if (m) {                                   // fast path
            int L = __ffsll(m) - 1;
            uint32_t wl = (uint32_t)__builtin_amdgcn_readlane((int)w, L);
            p = L * 32 + (__ffs(wl) - 1);
            positive = true;
        } else if (__ballot(nbhdW != 0u)) {        // rare: nbhd nonempty, all zeroed
            uint32_t nw = nbhdW, mo = 0xFFFFFFFFu; // -> min orig index among nbhd
            while (nw) {
                int k = __ffs(nw) - 1; nw &= nw - 1;
                mo = min(mo, ob[lane * 32 + k]);
            }
#pragma unroll
            for (int s = 32; s; s >>= 1)
                mo = min(mo, (uint32_t)__shfl_xor((int)mo, s, 64));
            p = (int)ib[mo];
            positive = false;
        } else {                                   // nbhd empty: global argmax
            u64 ma = __ballot(availW != 0u);
            if (ma) {
                int L = __ffsll(ma) - 1;
                uint32_t wl = (uint32_t)__builtin_amdgcn_readlane((int)availW, L);
                p = L * 32 + (__ffs(wl) - 1);
                positive = true;
            } else {                               // all conf zero -> argmax = idx 0
                p = (int)ib[0];
                positive = false;
            }
        }
        p = __builtin_amdgcn_readfirstlane(p);

        uint32_t rowW = rS[(size_t)p * 64 + lane];   // 256B coalesced (L2 after warm)
        uint32_t ogv  = ob[p];                        // uniform scalar load

        if (lane == 0) po[t] = (float)ogv;

        uint32_t pbit = (lane == (p >> 5)) ? (1u << (p & 31)) : 0u;
        if (positive) {
            availW &= ~pbit;                          // optimistic singleton clear
            uint32_t nsw = (uint32_t)__builtin_amdgcn_readlane((int)nonSingW, p >> 5);
            if ((nsw >> (p & 31)) & 1u) {             // rare tie-run: clear [rs,re]
                uint32_t ext = rE[p];
                int rs  = (int)(ext & 0xFFFFu);
                int ren = (int)(ext >> 16);
                int lo = rs - lane * 32;      lo = lo < 0 ? 0 : (lo > 32 ? 32 : lo);
                int hi = ren + 1 - lane * 32; hi = hi < 0 ? 0 : (hi > 32 ? 32 : hi);
                if (hi > lo) {
                    uint32_t mh = (hi >= 32) ? 0xFFFFFFFFu : ((1u << hi) - 1u);
                    uint32_t ml = (1u << lo) - 1u;
                    availW &= ~(mh & ~ml);
                }
            }
        }
        nbhdW = (nbhdW & ~pbit) | (rowW & unvisW);    // remove fc, add unvisited nbrs
        unvisW &= ~pbit;                              // visit fc
    }
}

// ===========================================================================
// Fallback (ws too small): direct-f32 greedy, contiguous-lane ownership.
// ===========================================================================
__global__ __launch_bounds__(64, 1) void k_greedy_fb(const float* __restrict__ confid,
                                                     const float* __restrict__ nb,
                                                     float* __restrict__ perm_out) {
    int b = blockIdx.x, lane = threadIdx.x;
    float conf[32];
    {
        const float* cb = confid + (size_t)b * NN * CC + (size_t)lane * 32 * CC;
#pragma unroll
        for (int k = 0; k < 32; k++) {
            const float4* p = (const float4*)(cb + k * CC);
            float4 a = p[0], c = p[1];
            conf[k] = fmaxf(fmaxf(fmaxf(a.x, a.y), fmaxf(a.z, a.w)),
                            fmaxf(fmaxf(c.x, c.y), fmaxf(c.z, c.w)));
        }
    }
    uint32_t nbhd = 0u, unvis = 0xFFFFFFFFu;
    const float* nbb = nb + (size_t)b * NN * NN;
    float* po = perm_out + (size_t)b * NN;
    for (int t = 0; t < NN; t++) {
        float bv = -1.0f; int bk = 0;
#pragma unroll
        for (int k = 0; k < 32; k++) {
            float v = ((nbhd >> k) & 1u) ? conf[k] : -1.0f;
            bool g = v > bv; bv = g ? v : bv; bk = g ? k : bk;
        }
        u64 pk = 0ULL;
        if (bv >= 0.0f)
            pk = ((u64)__float_as_uint(bv) << 32) | (unsigned)(NN - (lane * 32 + bk));
#pragma unroll
        for (int mm = 32; mm; mm >>= 1) {
            u64 o = __shfl_xor(pk, mm, 64);
            pk = (o > pk) ? o : pk;
        }
        if (pk == 0ULL) {
            float av = conf[0]; int ak = 0;
#pragma unroll
            for (int k = 1; k < 32; k++) {
                bool g = conf[k] > av; av = g ? conf[k] : av; ak = g ? k : ak;
            }
            u64 pa = ((u64)__float_as_uint(av) << 32) | (unsigned)(NN - (lane * 32 + ak));
#pragma unroll
            for (int mm = 32; mm; mm >>= 1) {
                u64 o = __shfl_xor(pa, mm, 64);
                pa = (o > pa) ? o : pa;
            }
            pk = pa;
        }
        int fc = NN - (int)(unsigned)(pk & 0xFFFFFFFFull);
        float cfc = __uint_as_float((unsigned)(pk >> 32));
        const float4* rp = (const float4*)(nbb + (size_t)fc * NN + lane * 32);
        uint32_t row = 0u;
#pragma unroll
        for (int j = 0; j < 8; j++) {
            float4 f = rp[j];
            row |= (f.x == 1.0f ? 1u : 0u) << (4 * j);
            row |= (f.y == 1.0f ? 1u : 0u) << (4 * j + 1);
            row |= (f.z == 1.0f ? 1u : 0u) << (4 * j + 2);
            row |= (f.w == 1.0f ? 1u : 0u) << (4 * j + 3);
        }
        if (lane == 0) po[t] = (float)fc;
        uint32_t mybit = (lane == (fc >> 5)) ? (1u << (fc & 31)) : 0u;
#pragma unroll
        for (int k = 0; k < 32; k++) conf[k] = (conf[k] == cfc) ? 0.0f : conf[k];
        nbhd = (nbhd & ~mybit) | (row & unvis);
        unvis &= ~mybit;
    }
}

// ===========================================================================
// K3: out0[b,t,:] = vertices[b, perm[t], :]
// ===========================================================================
__global__ __launch_bounds__(256) void k_gather(const float* __restrict__ vtx,
                                                const float* __restrict__ perm_f,
                                                float* __restrict__ out0) {
    int tid = blockIdx.x * 256 + threadIdx.x;
    int d = tid & (DD - 1);
    int t = (tid >> 7) & (NN - 1);
    int b = tid >> 18;
    int p = (int)perm_f[b * NN + t];
    out0[tid] = vtx[(((size_t)b * NN + p) << 7) + d];
}

// ===========================================================================
extern "C" void kernel_launch(void* const* d_in, const int* in_sizes, int n_in,
                              void* d_out, int out_size, void* d_ws, size_t ws_size,
                              hipStream_t stream) {
    const float* vertices   = (const float*)d_in[0];
    const float* confidence = (const float*)d_in[1];
    const float* neighbors  = (const float*)d_in[2];

    float* out0     = (float*)d_out;                   // [B,N,D]
    float* perm_out = out0 + (size_t)BB * NN * DD;     // [B,N] as f32 values

    const size_t rowS_bytes = (size_t)BB * NN * (NN / 8);   // 8 MB
    if (ws_size >= rowS_bytes) {
        uint32_t* rowS = (uint32_t*)d_ws;
        // temps live in the out0 region (fully overwritten by k_gather later):
        // bits 8MB | orig 128KB | inv 128KB | runExt 128KB | singBits 4KB  << 16MB
        uint32_t* bits     = (uint32_t*)out0;
        uint32_t* orig     = bits + (size_t)BB * NN * 64;
        uint32_t* inv      = orig + BB * NN;
        uint32_t* runExt   = inv + BB * NN;
        uint32_t* singBits = runExt + BB * NN;

        k_buildbits<<<BB * NN / 4, 256, 0, stream>>>(neighbors, bits);
        k_sort<<<BB, 256, 0, stream>>>(confidence, orig, inv, runExt, singBits);
        k_permbits<<<BB * NN / 128, 256, 0, stream>>>(bits, orig, rowS);
        k_greedy2<<<BB, 256, 0, stream>>>(rowS, orig, inv, runExt, singBits, perm_out);
    } else {
        k_greedy_fb<<<BB, 64, 0, stream>>>(confidence, neighbors, perm_out);
    }
    k_gather<<<(BB * NN * DD) / 256, 256, 0, stream>>>(vertices, perm_out, out0);
}